// Round 6
// baseline (230.460 us; speedup 1.0000x reference)
//
#include <hip/hip_runtime.h>
#include <math.h>

#define Bsz  2
#define Ntok 256
#define Ddim 512
#define Hdim 2048
#define Mrows 512

typedef __bf16 bf16_8 __attribute__((ext_vector_type(8)));
typedef __bf16 bf16_4 __attribute__((ext_vector_type(4)));
typedef float  f32x4_t __attribute__((ext_vector_type(4)));

// ---------------------------------------------------------------------------
// Prep kernel.
// [0,4608):    weight transpose+cast fp32 [K][N] -> bf16 [N][K]
// [4608,5632): distance partial sums (j split 4 ways), raw sums
// [5632,5888): zero d_out (1 MB) ; block 5632 also zeroes the grid-barrier ctr
// ---------------------------------------------------------------------------
struct PrepPtrs {
    const float* src[5];
    __bf16*      dst[5];
    const float* xv;
    const float* xa;
    float*       pv;    // [4][512]
    float*       pa;    // [4][512]
    float*       out;   // d_out, zeroed for P3 atomics
    unsigned*    ctr;   // grid barrier counter
};

__global__ __launch_bounds__(256) void prep_kernel(PrepPtrs p) {
    __shared__ float tile[32][33];
    __shared__ float red[4][4];

    int blk = blockIdx.x;
    int tid = threadIdx.x;

    if (blk < 4608) {
        // ---- transpose+cast ----
        const int Ks[5]  = {512, 512, 2048, 2048, 1024};
        const int Ns[5]  = {2048, 2048, 512, 512, 512};
        const int off[6] = {0, 1024, 2048, 3072, 4096, 4608};
        int mi = 0;
        while (blk >= off[mi + 1]) ++mi;
        int local = blk - off[mi];
        int shift = (mi < 2) ? 6 : 4;
        int bx = local & ((1 << shift) - 1);
        int by = local >> shift;
        const float* src = p.src[mi];
        __bf16*      dst = p.dst[mi];
        int K = Ks[mi], N = Ns[mi];
        int n0 = bx << 5, k0 = by << 5;

        int kl = tid >> 3, nl = (tid & 7) << 2;
        float4 v = *(const float4*)&src[(size_t)(k0 + kl) * N + n0 + nl];
        tile[kl][nl + 0] = v.x;
        tile[kl][nl + 1] = v.y;
        tile[kl][nl + 2] = v.z;
        tile[kl][nl + 3] = v.w;
        __syncthreads();
        int nl2 = tid >> 3, kl2 = (tid & 7) << 2;
        bf16_4 o;
#pragma unroll
        for (int i = 0; i < 4; ++i) o[i] = (__bf16)tile[kl2 + i][nl2];
        *(bf16_4*)&dst[(size_t)(n0 + nl2) * K + k0 + kl2] = o;
    } else if (blk < 5632) {
        // ---- distance partials ----
        int bx   = blk - 4608;
        int jc   = bx & 3;
        int g    = bx >> 2;
        int role = g >> 7;
        int b    = (g >> 6) & 1;
        int i0   = (g & 63) << 2;
        const float* Q    = role ? p.xa : p.xv;
        const float* S    = role ? p.xv : p.xa;
        float*       outp = role ? p.pa : p.pv;

        int d0 = tid << 1;
        const float* Qb = Q + ((size_t)b * Ntok + i0) * Ddim + d0;
        const float* Sb = S + ((size_t)b * Ntok + (jc << 6)) * Ddim + d0;

        float2 q[4];
#pragma unroll
        for (int r = 0; r < 4; ++r) q[r] = *(const float2*)(Qb + r * Ddim);

        float acc[4] = {0.f, 0.f, 0.f, 0.f};
#pragma unroll 4
        for (int j = 0; j < 64; ++j) {
            float2 s = *(const float2*)(Sb + (size_t)j * Ddim);
#pragma unroll
            for (int r = 0; r < 4; ++r)
                acc[r] += fabsf(q[r].x - s.x) + fabsf(q[r].y - s.y);
        }
        int lane = tid & 63, wv = tid >> 6;
#pragma unroll
        for (int r = 0; r < 4; ++r) {
            float v = acc[r];
#pragma unroll
            for (int off2 = 32; off2; off2 >>= 1) v += __shfl_down(v, off2);
            if (lane == 0) red[wv][r] = v;
        }
        __syncthreads();
        if (tid < 4) {
            float v = red[0][tid] + red[1][tid] + red[2][tid] + red[3][tid];
            outp[jc * Mrows + b * Ntok + i0 + tid] = v;
        }
    } else {
        // ---- zero d_out + ctr ----
        int zb = blk - 5632;                   // 0..255
        float4 z4 = {0.f, 0.f, 0.f, 0.f};
        *(float4*)&p.out[((size_t)zb * 256 + tid) * 4] = z4;
        if (zb == 0 && tid == 0) *p.ctr = 0u;
    }
}

// ---------------------------------------------------------------------------
// Grid barrier (all 256 blocks co-resident: 1 block/CU, 20 KB LDS).
// Monotonic counter; __threadfence() (device scope) + device-scope atomics
// give cross-XCD visibility (G16). atomicAdd(ctr,0) = atomic load.
// ---------------------------------------------------------------------------
__device__ __forceinline__ void gbar(unsigned* ctr, unsigned target) {
    __syncthreads();
    __threadfence();
    if (threadIdx.x == 0) {
        atomicAdd(ctr, 1u);
        while (atomicAdd(ctr, 0u) < target)
            __builtin_amdgcn_s_sleep(2);
    }
    __syncthreads();
    __threadfence();
}

// ---------------------------------------------------------------------------
// One 64x64 GEMM tile, 2-deep pipelined ping-pong LDS, BK=32.
// AMODE: 0 = bf16 A ; 1 = fp32 A scaled by mean-dist (scale4 partials) ;
//        2 = A = fp32 Aa + fp32 Ab (summed at staging)
// OUTM : 0 = fp32 store ; 1 = bf16 store ; 2 = fp32 atomicAdd
// ---------------------------------------------------------------------------
template <int GELU, int AMODE, int OUTM>
__device__ void gemm_tile(__bf16 (&As)[2][64][40], __bf16 (&Bs)[2][64][40],
                          const void* Aa, const void* Ab, int lda,
                          const __bf16* BT, int ldb,
                          const float* bias, const float* scale4,
                          void* C, int ldc, int Kdim,
                          int m0, int n0, int addBias) {
    const int tid = threadIdx.x;
    const int row = tid >> 2;        // 0..63
    const int kc  = (tid & 3) << 3;  // 0,8,16,24

    const __bf16* Bp  = BT + (size_t)(n0 + row) * ldb + kc;
    const float*  Af0 = nullptr;
    const float*  Af1 = nullptr;
    const __bf16* Abp = nullptr;
    float s = 1.0f;
    if (AMODE == 1) {
        Af0 = (const float*)Aa + (size_t)(m0 + row) * lda + kc;
        int m = m0 + row;
        s = (scale4[m] + scale4[Mrows + m] + scale4[2 * Mrows + m] +
             scale4[3 * Mrows + m]) * (1.0f / 256.0f);
    } else if (AMODE == 2) {
        Af0 = (const float*)Aa + (size_t)(m0 + row) * lda + kc;
        Af1 = (const float*)Ab + (size_t)(m0 + row) * lda + kc;
    } else {
        Abp = (const __bf16*)Aa + (size_t)(m0 + row) * lda + kc;
    }

    const int wave = tid >> 6, lane = tid & 63;
    const int moff = (wave >> 1) << 5, noff = (wave & 1) << 5;
    const int lrow = lane & 15, quad = lane >> 4;

    // staged regs: R = tile it+1 (stored to LDS this iter), N = tile it+2
    float4 rA0, rA1, rB0, rB1, nA0, nA1, nB0, nB1;   // fp32 paths
    bf16_8 ra8, na8;                                  // bf16 path
    bf16_8 rb8, nb8;                                  // B (always bf16)

    auto loadStage = [&](int kt, float4& fa0, float4& fa1, float4& fb0,
                         float4& fb1, bf16_8& a8, bf16_8& b8) {
        b8 = *(const bf16_8*)(Bp + kt);
        if (AMODE == 0) {
            a8 = *(const bf16_8*)(Abp + kt);
        } else {
            fa0 = *(const float4*)(Af0 + kt);
            fa1 = *(const float4*)(Af0 + kt + 4);
            if (AMODE == 2) {
                fb0 = *(const float4*)(Af1 + kt);
                fb1 = *(const float4*)(Af1 + kt + 4);
            }
        }
    };
    auto storeStage = [&](int buf, const float4& fa0, const float4& fa1,
                          const float4& fb0, const float4& fb1,
                          const bf16_8& a8in, const bf16_8& b8in) {
        bf16_8 a8;
        if (AMODE == 0) {
            a8 = a8in;
        } else if (AMODE == 1) {
            a8[0] = (__bf16)(fa0.x * s); a8[1] = (__bf16)(fa0.y * s);
            a8[2] = (__bf16)(fa0.z * s); a8[3] = (__bf16)(fa0.w * s);
            a8[4] = (__bf16)(fa1.x * s); a8[5] = (__bf16)(fa1.y * s);
            a8[6] = (__bf16)(fa1.z * s); a8[7] = (__bf16)(fa1.w * s);
        } else {
            a8[0] = (__bf16)(fa0.x + fb0.x); a8[1] = (__bf16)(fa0.y + fb0.y);
            a8[2] = (__bf16)(fa0.z + fb0.z); a8[3] = (__bf16)(fa0.w + fb0.w);
            a8[4] = (__bf16)(fa1.x + fb1.x); a8[5] = (__bf16)(fa1.y + fb1.y);
            a8[6] = (__bf16)(fa1.z + fb1.z); a8[7] = (__bf16)(fa1.w + fb1.w);
        }
        *(bf16_8*)&As[buf][row][kc] = a8;
        *(bf16_8*)&Bs[buf][row][kc] = b8in;
    };

    f32x4_t acc00 = {0.f, 0.f, 0.f, 0.f};
    f32x4_t acc01 = {0.f, 0.f, 0.f, 0.f};
    f32x4_t acc10 = {0.f, 0.f, 0.f, 0.f};
    f32x4_t acc11 = {0.f, 0.f, 0.f, 0.f};

    const int nIter = Kdim >> 5;

    __syncthreads();   // protect LDS reuse from previous tile/phase
    // prologue: stage tile 0, issue tile 1
    loadStage(0, rA0, rA1, rB0, rB1, ra8, rb8);
    storeStage(0, rA0, rA1, rB0, rB1, ra8, rb8);
    if (nIter > 1) loadStage(32, rA0, rA1, rB0, rB1, ra8, rb8);
    __syncthreads();

    for (int it = 0; it < nIter; ++it) {
        const int cur = it & 1;
        bf16_8 a0 = *(const bf16_8*)&As[cur][moff + lrow][quad << 3];
        bf16_8 a1 = *(const bf16_8*)&As[cur][moff + 16 + lrow][quad << 3];
        bf16_8 b0 = *(const bf16_8*)&Bs[cur][noff + lrow][quad << 3];
        bf16_8 b1 = *(const bf16_8*)&Bs[cur][noff + 16 + lrow][quad << 3];
        if (it + 2 < nIter)
            loadStage((it + 2) << 5, nA0, nA1, nB0, nB1, na8, nb8);
        acc00 = __builtin_amdgcn_mfma_f32_16x16x32_bf16(a0, b0, acc00, 0, 0, 0);
        acc01 = __builtin_amdgcn_mfma_f32_16x16x32_bf16(a0, b1, acc01, 0, 0, 0);
        acc10 = __builtin_amdgcn_mfma_f32_16x16x32_bf16(a1, b0, acc10, 0, 0, 0);
        acc11 = __builtin_amdgcn_mfma_f32_16x16x32_bf16(a1, b1, acc11, 0, 0, 0);
        if (it + 1 < nIter) {
            storeStage(cur ^ 1, rA0, rA1, rB0, rB1, ra8, rb8);
            rA0 = nA0; rA1 = nA1; rB0 = nB0; rB1 = nB1; ra8 = na8; rb8 = nb8;
            __syncthreads();
        }
    }

    f32x4_t accs[2][2] = {{acc00, acc01}, {acc10, acc11}};
#pragma unroll
    for (int ti = 0; ti < 2; ++ti) {
#pragma unroll
        for (int tj = 0; tj < 2; ++tj) {
            int colg = n0 + noff + (tj << 4) + lrow;
            float bv = addBias ? bias[colg] : 0.0f;
#pragma unroll
            for (int r = 0; r < 4; ++r) {
                int rowg = m0 + moff + (ti << 4) + (quad << 2) + r;
                float v = accs[ti][tj][r] + bv;
                if (GELU) v = 0.5f * v * (1.0f + erff(v * 0.70710678118654752f));
                if (OUTM == 1)
                    ((__bf16*)C)[(size_t)rowg * ldc + colg] = (__bf16)v;
                else if (OUTM == 0)
                    ((float*)C)[(size_t)rowg * ldc + colg] = v;
                else
                    atomicAdd((float*)C + (size_t)rowg * ldc + colg, v);
            }
        }
    }
}

// ---------------------------------------------------------------------------
// Fused persistent GEMM kernel: 256 blocks, 3 phases, 2 grid barriers.
// P1: g1[z] = gelu(diag(d)*x[z] @ W1[z] + b1[z])         512 tiles, 2/block
// P2: part[kz][:, z*512:] = g1[z][:,kzK] @ Wm[z][kzK,:]  256 tiles (splitK2)
// P3: out += (part0+part1)[:,kzK] @ Wout[kzK,:] (+bout)  256 tiles (splitK4)
// ---------------------------------------------------------------------------
struct FPtrs {
    const float*  x[2];
    const __bf16* WT1[2];    // [2048][512]
    const float*  b1[2];
    const float*  pd[2];     // pv, pa partial dist sums [4][512]
    __bf16*       g1[2];     // [512][2048]
    const __bf16* WTm[2];    // [512][2048]
    const float*  bm[2];
    float*        part[2];   // [512][1024] fp32
    const __bf16* WTout;     // [512][1024]
    const float*  bout;
    float*        out;       // [512][512] fp32, zeroed by prep
    unsigned*     ctr;
};

__global__ __launch_bounds__(256) void fused_gemms(FPtrs p) {
    __shared__ __align__(16) __bf16 As[2][64][40];
    __shared__ __align__(16) __bf16 Bs[2][64][40];
    const int blk = blockIdx.x;

    // ---- P1: GEMM1, 512 tiles (32n x 8m x 2z), 2 per block ----
    for (int t = blk; t < 512; t += 256) {
        int z  = t >> 8;
        int nt = t & 31, mt = (t >> 5) & 7;
        gemm_tile<1, 1, 1>(As, Bs, p.x[z], nullptr, Ddim, p.WT1[z], Ddim,
                           p.b1[z], p.pd[z], p.g1[z], Hdim, Ddim,
                           mt << 6, nt << 6, 1);
    }
    gbar(p.ctr, 256);

    // ---- P2: GEMM2 split-K x2, 256 tiles (8n x 8m x 2z x 2kz) ----
    {
        int nt = blk & 7, mt = (blk >> 3) & 7, z = (blk >> 6) & 1, kz = blk >> 7;
        gemm_tile<0, 0, 0>(As, Bs, p.g1[z] + kz * 1024, nullptr, Hdim,
                           p.WTm[z] + kz * 1024, Hdim, p.bm[z], nullptr,
                           p.part[kz] + z * Ddim, 2 * Ddim, 1024,
                           mt << 6, nt << 6, kz == 0);
    }
    gbar(p.ctr, 512);

    // ---- P3: GEMM3 split-K x4, 256 tiles (8n x 8m x 4kz) ----
    {
        int nt = blk & 7, mt = (blk >> 3) & 7, kz = blk >> 6;
        gemm_tile<0, 2, 2>(As, Bs, p.part[0] + kz * 256, p.part[1] + kz * 256,
                           2 * Ddim, p.WTout + kz * 256, 2 * Ddim, p.bout,
                           nullptr, p.out, Ddim, 256, mt << 6, nt << 6,
                           kz == 0);
    }
}

extern "C" void kernel_launch(void* const* d_in, const int* in_sizes, int n_in,
                              void* d_out, int out_size, void* d_ws, size_t ws_size,
                              hipStream_t stream) {
    const float* x_v  = (const float*)d_in[0];
    const float* x_a  = (const float*)d_in[1];
    const float* W1v  = (const float*)d_in[2];
    const float* b1v  = (const float*)d_in[3];
    const float* W1a  = (const float*)d_in[4];
    const float* b1a  = (const float*)d_in[5];
    const float* Wmv  = (const float*)d_in[6];
    const float* bmv  = (const float*)d_in[7];
    const float* Wma  = (const float*)d_in[8];
    const float* bma  = (const float*)d_in[9];
    const float* Wout = (const float*)d_in[10];
    const float* bout = (const float*)d_in[11];
    float* out = (float*)d_out;

    char* w = (char*)d_ws;
    auto alloc = [&](size_t bytes) {
        char* r = w;
        w += (bytes + 255) & ~(size_t)255;
        return (void*)r;
    };
    float*    pv    = (float*)alloc(4 * Mrows * 4);
    float*    pa    = (float*)alloc(4 * Mrows * 4);
    unsigned* ctr   = (unsigned*)alloc(256);
    __bf16*   WT1v  = (__bf16*)alloc((size_t)Hdim * Ddim * 2);
    __bf16*   WT1a  = (__bf16*)alloc((size_t)Hdim * Ddim * 2);
    __bf16*   WTmv  = (__bf16*)alloc((size_t)Ddim * Hdim * 2);
    __bf16*   WTma  = (__bf16*)alloc((size_t)Ddim * Hdim * 2);
    __bf16*   WTout = (__bf16*)alloc((size_t)Ddim * 2 * Ddim * 2);
    __bf16*   g1v   = (__bf16*)alloc((size_t)Mrows * Hdim * 2);
    __bf16*   g1a   = (__bf16*)alloc((size_t)Mrows * Hdim * 2);
    float*    part0 = (float*)alloc((size_t)Mrows * 2 * Ddim * 4);
    float*    part1 = (float*)alloc((size_t)Mrows * 2 * Ddim * 4);

    // 1) prep: transpose+cast, dist partials, zero d_out + barrier ctr
    PrepPtrs pp;
    pp.src[0] = W1v;  pp.dst[0] = WT1v;
    pp.src[1] = W1a;  pp.dst[1] = WT1a;
    pp.src[2] = Wmv;  pp.dst[2] = WTmv;
    pp.src[3] = Wma;  pp.dst[3] = WTma;
    pp.src[4] = Wout; pp.dst[4] = WTout;
    pp.xv = x_v; pp.xa = x_a; pp.pv = pv; pp.pa = pa;
    pp.out = out; pp.ctr = ctr;
    prep_kernel<<<dim3(5888), dim3(256), 0, stream>>>(pp);

    // 2) fused persistent 3-phase GEMM
    FPtrs fp;
    fp.x[0] = x_v; fp.x[1] = x_a;
    fp.WT1[0] = WT1v; fp.WT1[1] = WT1a;
    fp.b1[0] = b1v; fp.b1[1] = b1a;
    fp.pd[0] = pv; fp.pd[1] = pa;
    fp.g1[0] = g1v; fp.g1[1] = g1a;
    fp.WTm[0] = WTmv; fp.WTm[1] = WTma;
    fp.bm[0] = bmv; fp.bm[1] = bma;
    fp.part[0] = part0; fp.part[1] = part1;
    fp.WTout = WTout; fp.bout = bout;
    fp.out = out; fp.ctr = ctr;
    fused_gemms<<<dim3(256), dim3(256), 0, stream>>>(fp);
}

// Round 7
// 135.174 us; speedup vs baseline: 1.7049x; 1.7049x over previous
//
#include <hip/hip_runtime.h>
#include <math.h>

#define Bsz  2
#define Ntok 256
#define Ddim 512
#define Hdim 2048
#define Mrows 512

typedef __bf16 bf16_8 __attribute__((ext_vector_type(8)));
typedef __bf16 bf16_4 __attribute__((ext_vector_type(4)));
typedef float  f32x4_t __attribute__((ext_vector_type(4)));

// ---------------------------------------------------------------------------
// Prep kernel.
// [0,4608):    weight transpose+cast fp32 [K][N] -> bf16 [N][K]
// [4608,5632): distance partial sums (j split 4 ways), raw sums
// [5632,5888): zero d_out (1 MB) for GEMM3's atomicAdd accumulation
// ---------------------------------------------------------------------------
struct PrepPtrs {
    const float* src[5];
    __bf16*      dst[5];
    const float* xv;
    const float* xa;
    float*       pv;    // [4][512]
    float*       pa;    // [4][512]
    float*       out;   // d_out, zeroed for GEMM3 atomics
};

__global__ __launch_bounds__(256) void prep_kernel(PrepPtrs p) {
    __shared__ float tile[32][33];
    __shared__ float red[4][4];

    int blk = blockIdx.x;
    int tid = threadIdx.x;

    if (blk < 4608) {
        // ---- transpose+cast ----
        const int Ks[5]  = {512, 512, 2048, 2048, 1024};
        const int Ns[5]  = {2048, 2048, 512, 512, 512};
        const int off[6] = {0, 1024, 2048, 3072, 4096, 4608};
        int mi = 0;
        while (blk >= off[mi + 1]) ++mi;
        int local = blk - off[mi];
        int shift = (mi < 2) ? 6 : 4;
        int bx = local & ((1 << shift) - 1);
        int by = local >> shift;
        const float* src = p.src[mi];
        __bf16*      dst = p.dst[mi];
        int K = Ks[mi], N = Ns[mi];
        int n0 = bx << 5, k0 = by << 5;

        int kl = tid >> 3, nl = (tid & 7) << 2;
        float4 v = *(const float4*)&src[(size_t)(k0 + kl) * N + n0 + nl];
        tile[kl][nl + 0] = v.x;
        tile[kl][nl + 1] = v.y;
        tile[kl][nl + 2] = v.z;
        tile[kl][nl + 3] = v.w;
        __syncthreads();
        int nl2 = tid >> 3, kl2 = (tid & 7) << 2;
        bf16_4 o;
#pragma unroll
        for (int i = 0; i < 4; ++i) o[i] = (__bf16)tile[kl2 + i][nl2];
        *(bf16_4*)&dst[(size_t)(n0 + nl2) * K + k0 + kl2] = o;
    } else if (blk < 5632) {
        // ---- distance partials ----
        int bx   = blk - 4608;
        int jc   = bx & 3;
        int g    = bx >> 2;
        int role = g >> 7;
        int b    = (g >> 6) & 1;
        int i0   = (g & 63) << 2;
        const float* Q    = role ? p.xa : p.xv;
        const float* S    = role ? p.xv : p.xa;
        float*       outp = role ? p.pa : p.pv;

        int d0 = tid << 1;
        const float* Qb = Q + ((size_t)b * Ntok + i0) * Ddim + d0;
        const float* Sb = S + ((size_t)b * Ntok + (jc << 6)) * Ddim + d0;

        float2 q[4];
#pragma unroll
        for (int r = 0; r < 4; ++r) q[r] = *(const float2*)(Qb + r * Ddim);

        float acc[4] = {0.f, 0.f, 0.f, 0.f};
#pragma unroll 4
        for (int j = 0; j < 64; ++j) {
            float2 s = *(const float2*)(Sb + (size_t)j * Ddim);
#pragma unroll
            for (int r = 0; r < 4; ++r)
                acc[r] += fabsf(q[r].x - s.x) + fabsf(q[r].y - s.y);
        }
        int lane = tid & 63, wv = tid >> 6;
#pragma unroll
        for (int r = 0; r < 4; ++r) {
            float v = acc[r];
#pragma unroll
            for (int off2 = 32; off2; off2 >>= 1) v += __shfl_down(v, off2);
            if (lane == 0) red[wv][r] = v;
        }
        __syncthreads();
        if (tid < 4) {
            float v = red[0][tid] + red[1][tid] + red[2][tid] + red[3][tid];
            outp[jc * Mrows + b * Ntok + i0 + tid] = v;
        }
    } else {
        // ---- zero d_out ----
        int zb = blk - 5632;                   // 0..255
        float4 z4 = {0.f, 0.f, 0.f, 0.f};
        *(float4*)&p.out[((size_t)zb * 256 + tid) * 4] = z4;
    }
}

// ---------------------------------------------------------------------------
// One 64x64 GEMM tile, 2-deep pipelined ping-pong LDS, BK=32.
// AMODE: 0 = bf16 A ; 1 = fp32 A scaled by mean-dist (scale4 partials) ;
//        2 = A = fp32 Aa + fp32 Ab (summed at staging)
// OUTM : 0 = fp32 store ; 1 = bf16 store ; 2 = fp32 atomicAdd
// (all three mode combos numerically verified in R6's fused run, absmax 2.0)
// ---------------------------------------------------------------------------
template <int GELU, int AMODE, int OUTM>
__device__ void gemm_tile(__bf16 (&As)[2][64][40], __bf16 (&Bs)[2][64][40],
                          const void* Aa, const void* Ab, int lda,
                          const __bf16* BT, int ldb,
                          const float* bias, const float* scale4,
                          void* C, int ldc, int Kdim,
                          int m0, int n0, int addBias) {
    const int tid = threadIdx.x;
    const int row = tid >> 2;        // 0..63
    const int kc  = (tid & 3) << 3;  // 0,8,16,24

    const __bf16* Bp  = BT + (size_t)(n0 + row) * ldb + kc;
    const float*  Af0 = nullptr;
    const float*  Af1 = nullptr;
    const __bf16* Abp = nullptr;
    float s = 1.0f;
    if (AMODE == 1) {
        Af0 = (const float*)Aa + (size_t)(m0 + row) * lda + kc;
        int m = m0 + row;
        s = (scale4[m] + scale4[Mrows + m] + scale4[2 * Mrows + m] +
             scale4[3 * Mrows + m]) * (1.0f / 256.0f);
    } else if (AMODE == 2) {
        Af0 = (const float*)Aa + (size_t)(m0 + row) * lda + kc;
        Af1 = (const float*)Ab + (size_t)(m0 + row) * lda + kc;
    } else {
        Abp = (const __bf16*)Aa + (size_t)(m0 + row) * lda + kc;
    }

    const int wave = tid >> 6, lane = tid & 63;
    const int moff = (wave >> 1) << 5, noff = (wave & 1) << 5;
    const int lrow = lane & 15, quad = lane >> 4;

    // staged regs: R = tile it+1 (stored to LDS this iter), N = tile it+2
    float4 rA0, rA1, rB0, rB1, nA0, nA1, nB0, nB1;   // fp32 paths
    bf16_8 ra8, na8;                                  // bf16 path
    bf16_8 rb8, nb8;                                  // B (always bf16)

    auto loadStage = [&](int kt, float4& fa0, float4& fa1, float4& fb0,
                         float4& fb1, bf16_8& a8, bf16_8& b8) {
        b8 = *(const bf16_8*)(Bp + kt);
        if (AMODE == 0) {
            a8 = *(const bf16_8*)(Abp + kt);
        } else {
            fa0 = *(const float4*)(Af0 + kt);
            fa1 = *(const float4*)(Af0 + kt + 4);
            if (AMODE == 2) {
                fb0 = *(const float4*)(Af1 + kt);
                fb1 = *(const float4*)(Af1 + kt + 4);
            }
        }
    };
    auto storeStage = [&](int buf, const float4& fa0, const float4& fa1,
                          const float4& fb0, const float4& fb1,
                          const bf16_8& a8in, const bf16_8& b8in) {
        bf16_8 a8;
        if (AMODE == 0) {
            a8 = a8in;
        } else if (AMODE == 1) {
            a8[0] = (__bf16)(fa0.x * s); a8[1] = (__bf16)(fa0.y * s);
            a8[2] = (__bf16)(fa0.z * s); a8[3] = (__bf16)(fa0.w * s);
            a8[4] = (__bf16)(fa1.x * s); a8[5] = (__bf16)(fa1.y * s);
            a8[6] = (__bf16)(fa1.z * s); a8[7] = (__bf16)(fa1.w * s);
        } else {
            a8[0] = (__bf16)(fa0.x + fb0.x); a8[1] = (__bf16)(fa0.y + fb0.y);
            a8[2] = (__bf16)(fa0.z + fb0.z); a8[3] = (__bf16)(fa0.w + fb0.w);
            a8[4] = (__bf16)(fa1.x + fb1.x); a8[5] = (__bf16)(fa1.y + fb1.y);
            a8[6] = (__bf16)(fa1.z + fb1.z); a8[7] = (__bf16)(fa1.w + fb1.w);
        }
        *(bf16_8*)&As[buf][row][kc] = a8;
        *(bf16_8*)&Bs[buf][row][kc] = b8in;
    };

    f32x4_t acc00 = {0.f, 0.f, 0.f, 0.f};
    f32x4_t acc01 = {0.f, 0.f, 0.f, 0.f};
    f32x4_t acc10 = {0.f, 0.f, 0.f, 0.f};
    f32x4_t acc11 = {0.f, 0.f, 0.f, 0.f};

    const int nIter = Kdim >> 5;

    // prologue: stage tile 0, issue tile 1
    loadStage(0, rA0, rA1, rB0, rB1, ra8, rb8);
    storeStage(0, rA0, rA1, rB0, rB1, ra8, rb8);
    if (nIter > 1) loadStage(32, rA0, rA1, rB0, rB1, ra8, rb8);
    __syncthreads();

    for (int it = 0; it < nIter; ++it) {
        const int cur = it & 1;
        bf16_8 a0 = *(const bf16_8*)&As[cur][moff + lrow][quad << 3];
        bf16_8 a1 = *(const bf16_8*)&As[cur][moff + 16 + lrow][quad << 3];
        bf16_8 b0 = *(const bf16_8*)&Bs[cur][noff + lrow][quad << 3];
        bf16_8 b1 = *(const bf16_8*)&Bs[cur][noff + 16 + lrow][quad << 3];
        if (it + 2 < nIter)
            loadStage((it + 2) << 5, nA0, nA1, nB0, nB1, na8, nb8);
        acc00 = __builtin_amdgcn_mfma_f32_16x16x32_bf16(a0, b0, acc00, 0, 0, 0);
        acc01 = __builtin_amdgcn_mfma_f32_16x16x32_bf16(a0, b1, acc01, 0, 0, 0);
        acc10 = __builtin_amdgcn_mfma_f32_16x16x32_bf16(a1, b0, acc10, 0, 0, 0);
        acc11 = __builtin_amdgcn_mfma_f32_16x16x32_bf16(a1, b1, acc11, 0, 0, 0);
        if (it + 1 < nIter) {
            storeStage(cur ^ 1, rA0, rA1, rB0, rB1, ra8, rb8);
            rA0 = nA0; rA1 = nA1; rB0 = nB0; rB1 = nB1; ra8 = na8; rb8 = nb8;
            __syncthreads();
        }
    }

    f32x4_t accs[2][2] = {{acc00, acc01}, {acc10, acc11}};
#pragma unroll
    for (int ti = 0; ti < 2; ++ti) {
#pragma unroll
        for (int tj = 0; tj < 2; ++tj) {
            int colg = n0 + noff + (tj << 4) + lrow;
            float bv = addBias ? bias[colg] : 0.0f;
#pragma unroll
            for (int r = 0; r < 4; ++r) {
                int rowg = m0 + moff + (ti << 4) + (quad << 2) + r;
                float v = accs[ti][tj][r] + bv;
                if (GELU) v = 0.5f * v * (1.0f + erff(v * 0.70710678118654752f));
                if (OUTM == 1)
                    ((__bf16*)C)[(size_t)rowg * ldc + colg] = (__bf16)v;
                else if (OUTM == 0)
                    ((float*)C)[(size_t)rowg * ldc + colg] = v;
                else
                    atomicAdd((float*)C + (size_t)rowg * ldc + colg, v);
            }
        }
    }
}

// ---------------------------------------------------------------------------
// Phase kernels (separate launches — HW kernel-boundary sync beats software
// grid barriers by ~65 us/barrier, measured R6).
// ---------------------------------------------------------------------------
struct FPtrs {
    const float*  x[2];
    const __bf16* WT1[2];    // [2048][512]
    const float*  b1[2];
    const float*  pd[2];     // pv, pa partial dist sums [4][512]
    __bf16*       g1[2];     // [512][2048]
    const __bf16* WTm[2];    // [512][2048]
    const float*  bm[2];
    float*        part[2];   // [512][1024] fp32
    const __bf16* WTout;     // [512][1024]
    const float*  bout;
    float*        out;       // [512][512] fp32, zeroed by prep
};

// P1: g1[z] = gelu(diag(d)*x[z] @ W1[z] + b1[z]); grid (32,8,2) = 512 blocks
__global__ __launch_bounds__(256) void gemm1_kernel(FPtrs p) {
    __shared__ __align__(16) __bf16 As[2][64][40];
    __shared__ __align__(16) __bf16 Bs[2][64][40];
    int z = blockIdx.z;
    gemm_tile<1, 1, 1>(As, Bs, p.x[z], nullptr, Ddim, p.WT1[z], Ddim,
                       p.b1[z], p.pd[z], p.g1[z], Hdim, Ddim,
                       blockIdx.y << 6, blockIdx.x << 6, 1);
}

// P2: part[kz][:, z*512:] = g1[z][:, kz*1024:] @ Wm[z][kz*1024:, :] (+bm@kz0)
// grid (8,8,4): z = zz&1, kz = zz>>1 -> 256 blocks, 32 iters each
__global__ __launch_bounds__(256) void gemm2_kernel(FPtrs p) {
    __shared__ __align__(16) __bf16 As[2][64][40];
    __shared__ __align__(16) __bf16 Bs[2][64][40];
    int zz = blockIdx.z, z = zz & 1, kz = zz >> 1;
    gemm_tile<0, 0, 0>(As, Bs, p.g1[z] + kz * 1024, nullptr, Hdim,
                       p.WTm[z] + kz * 1024, Hdim, p.bm[z], nullptr,
                       p.part[kz] + z * Ddim, 2 * Ddim, 1024,
                       blockIdx.y << 6, blockIdx.x << 6, kz == 0);
}

// P3: out += (part0+part1)[:, kz*256:] @ Wout[kz*256:, :] (+bout@kz0)
// grid (8,8,4): kz = blockIdx.z -> 256 blocks, 8 iters each, atomicAdd out
__global__ __launch_bounds__(256) void gemm3_kernel(FPtrs p) {
    __shared__ __align__(16) __bf16 As[2][64][40];
    __shared__ __align__(16) __bf16 Bs[2][64][40];
    int kz = blockIdx.z;
    gemm_tile<0, 2, 2>(As, Bs, p.part[0] + kz * 256, p.part[1] + kz * 256,
                       2 * Ddim, p.WTout + kz * 256, 2 * Ddim, p.bout,
                       nullptr, p.out, Ddim, 256,
                       blockIdx.y << 6, blockIdx.x << 6, kz == 0);
}

extern "C" void kernel_launch(void* const* d_in, const int* in_sizes, int n_in,
                              void* d_out, int out_size, void* d_ws, size_t ws_size,
                              hipStream_t stream) {
    const float* x_v  = (const float*)d_in[0];
    const float* x_a  = (const float*)d_in[1];
    const float* W1v  = (const float*)d_in[2];
    const float* b1v  = (const float*)d_in[3];
    const float* W1a  = (const float*)d_in[4];
    const float* b1a  = (const float*)d_in[5];
    const float* Wmv  = (const float*)d_in[6];
    const float* bmv  = (const float*)d_in[7];
    const float* Wma  = (const float*)d_in[8];
    const float* bma  = (const float*)d_in[9];
    const float* Wout = (const float*)d_in[10];
    const float* bout = (const float*)d_in[11];
    float* out = (float*)d_out;

    char* w = (char*)d_ws;
    auto alloc = [&](size_t bytes) {
        char* r = w;
        w += (bytes + 255) & ~(size_t)255;
        return (void*)r;
    };
    float*    pv    = (float*)alloc(4 * Mrows * 4);
    float*    pa    = (float*)alloc(4 * Mrows * 4);
    __bf16*   WT1v  = (__bf16*)alloc((size_t)Hdim * Ddim * 2);
    __bf16*   WT1a  = (__bf16*)alloc((size_t)Hdim * Ddim * 2);
    __bf16*   WTmv  = (__bf16*)alloc((size_t)Ddim * Hdim * 2);
    __bf16*   WTma  = (__bf16*)alloc((size_t)Ddim * Hdim * 2);
    __bf16*   WTout = (__bf16*)alloc((size_t)Ddim * 2 * Ddim * 2);
    __bf16*   g1v   = (__bf16*)alloc((size_t)Mrows * Hdim * 2);
    __bf16*   g1a   = (__bf16*)alloc((size_t)Mrows * Hdim * 2);
    float*    part0 = (float*)alloc((size_t)Mrows * 2 * Ddim * 4);
    float*    part1 = (float*)alloc((size_t)Mrows * 2 * Ddim * 4);

    // 1) prep: transpose+cast, dist partials, zero d_out
    PrepPtrs pp;
    pp.src[0] = W1v;  pp.dst[0] = WT1v;
    pp.src[1] = W1a;  pp.dst[1] = WT1a;
    pp.src[2] = Wmv;  pp.dst[2] = WTmv;
    pp.src[3] = Wma;  pp.dst[3] = WTma;
    pp.src[4] = Wout; pp.dst[4] = WTout;
    pp.xv = x_v; pp.xa = x_a; pp.pv = pv; pp.pa = pa;
    pp.out = out;
    prep_kernel<<<dim3(5888), dim3(256), 0, stream>>>(pp);

    FPtrs fp;
    fp.x[0] = x_v; fp.x[1] = x_a;
    fp.WT1[0] = WT1v; fp.WT1[1] = WT1a;
    fp.b1[0] = b1v; fp.b1[1] = b1a;
    fp.pd[0] = pv; fp.pd[1] = pa;
    fp.g1[0] = g1v; fp.g1[1] = g1a;
    fp.WTm[0] = WTmv; fp.WTm[1] = WTma;
    fp.bm[0] = bmv; fp.bm[1] = bma;
    fp.part[0] = part0; fp.part[1] = part1;
    fp.WTout = WTout; fp.bout = bout;
    fp.out = out;

    // 2-4) three GEMM phases, stream-serialized
    gemm1_kernel<<<dim3(Hdim / 64, Mrows / 64, 2), dim3(256), 0, stream>>>(fp);
    gemm2_kernel<<<dim3(8, 8, 4), dim3(256), 0, stream>>>(fp);
    gemm3_kernel<<<dim3(8, 8, 4), dim3(256), 0, stream>>>(fp);
}